// Round 13
// baseline (439.663 us; speedup 1.0000x reference)
//
#include <hip/hip_runtime.h>
#include <math.h>

#define T_STEPS 48
#define N_NODES 1000
#define E_EDGES 32000
#define DIN     32
#define H_DIM   64

// ---- workspace layout (4-byte units) ----
#define O_INDEG  0         // int[1000]
#define O_FILL   1024      // int[1000]
#define O_ROWPTR 2048      // int[1001]
#define O_CSRC   4096      // int[32000]
#define O_CNORM  36864     // f32[32000]
#define O_DINV   69632     // f32[1000]
#define O_SELF   70656     // f32[1000]
#define O_BUF0   71680                    // f32[48*64000]  T1 -> T2 -> HS
#define O_BUF1   (71680 + 3072000)        // f32[48*64000]  G1 -> G2 -> part

__device__ __forceinline__ float sigmf(float v) { return 1.0f / (1.0f + __expf(-v)); }

// global -> LDS direct (16B per lane); dest must be wave-uniform base + lane*16
__device__ __forceinline__ void gld16(const void* g, void* l) {
  __builtin_amdgcn_global_load_lds((const __attribute__((address_space(1))) void*)g,
                                   (__attribute__((address_space(3))) void*)l, 16, 0, 0);
}

// ---------------- setup ----------------
__global__ void k_zero(int* __restrict__ p) { p[blockIdx.x * 256 + threadIdx.x] = 0; }

__global__ void k_count(const int* __restrict__ ei, int* __restrict__ indeg) {
  int e = blockIdx.x * 256 + threadIdx.x;
  if (e < E_EDGES) atomicAdd(&indeg[ei[E_EDGES + e]], 1);
}

__global__ void k_scan(const int* __restrict__ indeg, int* __restrict__ rowptr,
                       float* __restrict__ dinv, float* __restrict__ selfn) {
  __shared__ int sdat[1024];
  int tid = threadIdx.x;
  int v = (tid < N_NODES) ? indeg[tid] : 0;
  sdat[tid] = v;
  __syncthreads();
  for (int off = 1; off < 1024; off <<= 1) {
    int add = (tid >= off) ? sdat[tid - off] : 0;
    __syncthreads();
    sdat[tid] += add;
    __syncthreads();
  }
  if (tid < N_NODES) {
    rowptr[tid + 1] = sdat[tid];
    float di = rsqrtf((float)(v + 1));
    dinv[tid] = di;
    selfn[tid] = di * di;
  }
  if (tid == 0) rowptr[0] = 0;
}

__global__ void k_scatter(const int* __restrict__ ei, const int* __restrict__ rowptr,
                          int* __restrict__ fill, const float* __restrict__ dinv,
                          int* __restrict__ csrc, float* __restrict__ cnorm) {
  int e = blockIdx.x * 256 + threadIdx.x;
  if (e >= E_EDGES) return;
  int s = ei[e], d = ei[E_EDGES + e];
  int pos = atomicAdd(&fill[d], 1);
  int idx = rowptr[d] + pos;
  csrc[idx] = s;
  cnorm[idx] = dinv[s] * dinv[d];
}

// ---------------- T1 = x @ Wg1 ----------------
__global__ void __launch_bounds__(256) k_t1(const float* __restrict__ x,
                                            const float* __restrict__ Wg1,
                                            float* __restrict__ T1) {
  __shared__ float sWT[H_DIM * 36];     // transposed: sWT[h][k]
  __shared__ float sx[4][DIN];
  const int tid = threadIdx.x, wv = tid >> 6, h = tid & 63;
  for (int i = tid; i < DIN * H_DIM; i += 256) sWT[(i & 63) * 36 + (i >> 6)] = Wg1[i];
  __syncthreads();
  const int r0 = blockIdx.x * 64 + wv * 16;
  const float4* wrow = (const float4*)&sWT[h * 36];
  for (int it = 0; it < 16; ++it) {
    const int r = r0 + it;
    if (h < DIN) sx[wv][h] = x[r * DIN + h];   // wave-local
    float acc = 0.f;
    const float4* xp = (const float4*)&sx[wv][0];
#pragma unroll
    for (int k4 = 0; k4 < 8; ++k4) {
      float4 xv = xp[k4], wv4 = wrow[k4];
      acc += xv.x * wv4.x + xv.y * wv4.y + xv.z * wv4.z + xv.w * wv4.w;
    }
    T1[r * H_DIM + h] = acc;
  }
}

// ---------------- gather: dst = gather(Tsrc)+self+bias, optional relu ----------------
// 8-deep rotating prefetch: batch k+1's loads issue while batch k's FMAs run.
__device__ __forceinline__ float gath_node(const float* __restrict__ Tsrc,
                                           const int* __restrict__ es,
                                           const float* __restrict__ ew,
                                           int cnt, int h) {
  float a0 = 0.f, a1 = 0.f, a2 = 0.f, a3 = 0.f;
  float a4 = 0.f, a5 = 0.f, a6 = 0.f, a7 = 0.f;
  int e = 0;
  if (cnt >= 8) {
    float p0 = Tsrc[es[0] * 64 + h], p1 = Tsrc[es[1] * 64 + h];
    float p2 = Tsrc[es[2] * 64 + h], p3 = Tsrc[es[3] * 64 + h];
    float p4 = Tsrc[es[4] * 64 + h], p5 = Tsrc[es[5] * 64 + h];
    float p6 = Tsrc[es[6] * 64 + h], p7 = Tsrc[es[7] * 64 + h];
    for (e = 8; e + 8 <= cnt; e += 8) {
      float n0 = Tsrc[es[e + 0] * 64 + h], n1 = Tsrc[es[e + 1] * 64 + h];
      float n2 = Tsrc[es[e + 2] * 64 + h], n3 = Tsrc[es[e + 3] * 64 + h];
      float n4 = Tsrc[es[e + 4] * 64 + h], n5 = Tsrc[es[e + 5] * 64 + h];
      float n6 = Tsrc[es[e + 6] * 64 + h], n7 = Tsrc[es[e + 7] * 64 + h];
      a0 += ew[e - 8] * p0; a1 += ew[e - 7] * p1;
      a2 += ew[e - 6] * p2; a3 += ew[e - 5] * p3;
      a4 += ew[e - 4] * p4; a5 += ew[e - 3] * p5;
      a6 += ew[e - 2] * p6; a7 += ew[e - 1] * p7;
      p0 = n0; p1 = n1; p2 = n2; p3 = n3; p4 = n4; p5 = n5; p6 = n6; p7 = n7;
    }
    a0 += ew[e - 8] * p0; a1 += ew[e - 7] * p1;
    a2 += ew[e - 6] * p2; a3 += ew[e - 5] * p3;
    a4 += ew[e - 4] * p4; a5 += ew[e - 3] * p5;
    a6 += ew[e - 2] * p6; a7 += ew[e - 1] * p7;
  }
  for (; e < cnt; ++e) a0 += ew[e] * Tsrc[es[e] * 64 + h];
  return ((a0 + a1) + (a2 + a3)) + ((a4 + a5) + (a6 + a7));
}

// 16 nodes / block -> 3072 blocks for latency-hiding TLP
#define ECHUNK 768
__global__ void __launch_bounds__(256) k_gath(const float* __restrict__ Tall,
                                              const float* __restrict__ bias,
                                              const int* __restrict__ rowptr,
                                              const int* __restrict__ csrc,
                                              const float* __restrict__ cnorm,
                                              const float* __restrict__ selfn,
                                              float* __restrict__ Dall, int relu) {
  __shared__ int   s_src[ECHUNK];
  __shared__ float s_wt[ECHUNK];
  __shared__ float sb[64];
  const int tid = threadIdx.x, wv = tid >> 6, h = tid & 63;
  if (tid < 64) sb[tid] = bias[tid];
  const int t = blockIdx.x >> 6, nb16 = (blockIdx.x & 63) * 16;
  if (nb16 >= N_NODES) return;
  const float* Tsrc = Tall + t * 64000;
  float* dst = Dall + t * 64000;
  const int nE = (nb16 + 16 < N_NODES) ? nb16 + 16 : N_NODES;
  const int r0 = rowptr[nb16], r1 = rowptr[nE];
  const int tot = r1 - r0;
  const bool fits = (tot <= ECHUNK);
  if (fits)
    for (int i = tid; i < tot; i += 256) { s_src[i] = csrc[r0 + i]; s_wt[i] = cnorm[r0 + i]; }
  __syncthreads();
  for (int i = 0; i < 4; ++i) {
    const int n = nb16 + wv * 4 + i;
    if (n >= N_NODES) continue;
    const int a = rowptr[n], b = rowptr[n + 1];
    float acc = selfn[n] * Tsrc[n * 64 + h];
    if (fits) {
      acc += gath_node(Tsrc, s_src + (a - r0), s_wt + (a - r0), b - a, h);
    } else {
      for (int e = a; e < b; ++e) acc += cnorm[e] * Tsrc[csrc[e] * 64 + h];
    }
    acc += sb[h];
    if (relu) acc = fmaxf(acc, 0.f);
    dst[n * 64 + h] = acc;
  }
}

// ---------------- T2 = G1 @ Wg2 (48000 x 64 x 64) ----------------
__global__ void __launch_bounds__(256) k_mm2(const float* __restrict__ G1,
                                             const float* __restrict__ Wg2,
                                             float* __restrict__ T2) {
  __shared__ float sW[H_DIM * H_DIM];   // [k][h] broadcast form, conflict-free
  __shared__ float sx[4][H_DIM];
  const int tid = threadIdx.x, wv = tid >> 6, h = tid & 63;
  for (int i = tid; i < H_DIM * H_DIM; i += 256) sW[i] = Wg2[i];
  __syncthreads();
  const int r0 = blockIdx.x * 64 + wv * 16;
  for (int it = 0; it < 16; ++it) {
    const int r = r0 + it;
    sx[wv][h] = G1[r * 64 + h];   // wave-local write then read
    float acc = 0.f;
#pragma unroll
    for (int k = 0; k < H_DIM; ++k) acc += sx[wv][k] * sW[k * H_DIM + h];
    T2[r * 64 + h] = acc;
  }
}

// ---------------- LSTM scan: 1 node / block ----------------
__global__ void __launch_bounds__(256) k_lstm(const float* __restrict__ G2,
                                              const float* __restrict__ h0,
                                              const float* __restrict__ c0,
                                              const float* __restrict__ Wih,
                                              const float* __restrict__ Whh,
                                              const float* __restrict__ bih,
                                              const float* __restrict__ bhh,
                                              float* __restrict__ hsg,
                                              float* __restrict__ outp) {
  const int tid = threadIdx.x, nb = blockIdx.x;
  __shared__ float sh[64];
  __shared__ float sg2[2][64];
  __shared__ float sgates[256];
  float4 Wih4[16], Whh4[16];
  {
    const float4* wp = (const float4*)(Wih + tid * H_DIM);
    const float4* vp = (const float4*)(Whh + tid * H_DIM);
#pragma unroll
    for (int k = 0; k < 16; ++k) { Wih4[k] = wp[k]; Whh4[k] = vp[k]; }
  }
  const float bsum = bih[tid] + bhh[tid];
  float creg = 0.f;
  if (tid < 64) {
    sh[tid] = h0[nb * 64 + tid];
    creg = c0[nb * 64 + tid];
    sg2[0][tid] = G2[nb * 64 + tid];
  }
  __syncthreads();
  for (int t = 0; t < T_STEPS; ++t) {
    const int cur = t & 1;
    float gnext = 0.f;
    if (t < T_STEPS - 1 && tid < 64) gnext = G2[(t + 1) * 64000 + nb * 64 + tid];
    float gv = bsum;
    const float4* gp = (const float4*)&sg2[cur][0];
    const float4* hp = (const float4*)sh;
#pragma unroll
    for (int k = 0; k < 16; ++k) {
      float4 a = gp[k], b = hp[k];
      gv += a.x * Wih4[k].x + a.y * Wih4[k].y + a.z * Wih4[k].z + a.w * Wih4[k].w;
      gv += b.x * Whh4[k].x + b.y * Whh4[k].y + b.z * Whh4[k].z + b.w * Whh4[k].w;
    }
    sgates[tid] = gv;
    __syncthreads();
    if (tid < 64) {
      float iv = sgates[tid], fv = sgates[64 + tid], gg = sgates[128 + tid], ov = sgates[192 + tid];
      float cn = sigmf(fv) * creg + sigmf(iv) * tanhf(gg);
      float hn = sigmf(ov) * tanhf(cn);
      creg = cn;
      sh[tid] = hn;
      hsg[t * 64000 + nb * 64 + tid] = hn;
      if (t < T_STEPS - 1) sg2[cur ^ 1][tid] = gnext;
    }
    __syncthreads();
  }
  if (tid < 64) {
    outp[48000 + nb * 64 + tid] = sh[tid];
    outp[48000 + 64000 + nb * 64 + tid] = creg;
  }
}

// ---------------- final projection: out = HS @ Wlin^T ----------------
// Block-shared gld16 staging + counted vmcnt + RAW s_barrier (no drain).
// Per mt: issue 7 loads (3 HS stages + 4 W b128) -> vmcnt(7) waits only for the
// PREVIOUS mt's 7 -> s_barrier -> compute -> s_barrier. Just-issued loads stay
// in flight across both barriers (T4). grid 2520 = kc40 x ng63.
// R12 fix: COMPUTE reads row (t0+u), not u.
#define KC4 40
__global__ void __launch_bounds__(256) k_gemm10(const float* __restrict__ hsg,
                                                const float* __restrict__ Wlin,
                                                float* __restrict__ part) {
  __shared__ float lds[2][3072];          // double-buffered HS tile [48][64]
  const int tid = threadIdx.x;
  const int kc = blockIdx.x % KC4;        // same kc -> same XCD (40 % 8 == 0)
  const int ng = blockIdx.x / KC4;        // 0..62
  const int nbase = ng * 16;
  const int kcbase = kc * 1600;           // 64000 / 40
  const int ks = tid & 15, nq = (tid >> 4) & 3, tq = tid >> 6;
  const int t0 = tq * 12;
  const int m4 = ks * 4;

  // HS staging source: round r stages row r*16 + (tid>>4), col f4 = tid&15
  const float* hsrc = hsg + (size_t)(tid >> 4) * 64000 + kcbase + 4 * (tid & 15);

  const float* wrow[4];
#pragma unroll
  for (int j = 0; j < 4; ++j) {
    int ngl = nbase + nq * 4 + j;
    if (ngl > N_NODES - 1) ngl = N_NODES - 1;   // dup rows computed, never written
    wrow[j] = Wlin + (size_t)ngl * 64000 + kcbase + m4;
  }

  float acc[4][12];
#pragma unroll
  for (int j = 0; j < 4; ++j)
#pragma unroll
    for (int u = 0; u < 12; ++u) acc[j][u] = 0.f;

  float4 WA[4], WB[4];

#define STAGE10(db, mo)                                               \
  {                                                                   \
    gld16(hsrc + (mo), (db) + 4 * tid);                               \
    gld16(hsrc + (size_t)16 * 64000 + (mo), (db) + 1024 + 4 * tid);   \
    gld16(hsrc + (size_t)32 * 64000 + (mo), (db) + 2048 + 4 * tid);   \
  }
#define LOADW10(W, mo)                                                \
  {                                                                   \
    _Pragma("unroll")                                                 \
    for (int j = 0; j < 4; ++j) W[j] = *(const float4*)(wrow[j] + (mo)); \
  }
// counted wait: previous mt's 7 ops complete; this mt's 7 stay in flight
#define SYNC_PRE                                                      \
  asm volatile("s_waitcnt vmcnt(7)" ::: "memory");                    \
  __builtin_amdgcn_sched_barrier(0);                                  \
  __builtin_amdgcn_s_barrier();                                       \
  __builtin_amdgcn_sched_barrier(0);
#define SYNC_POST                                                     \
  __builtin_amdgcn_sched_barrier(0);                                  \
  __builtin_amdgcn_s_barrier();                                       \
  __builtin_amdgcn_sched_barrier(0);
#define COMPUTE10(db, W)                                              \
  {                                                                   \
    _Pragma("unroll")                                                 \
    for (int u = 0; u < 12; ++u) {                                    \
      const float4 h4 = *(const float4*)((db) + (t0 + u) * 64 + m4);  \
      _Pragma("unroll")                                               \
      for (int j = 0; j < 4; ++j)                                     \
        acc[j][u] += W[j].x * h4.x + W[j].y * h4.y +                  \
                     W[j].z * h4.z + W[j].w * h4.w;                   \
    }                                                                 \
  }

  STAGE10(lds[0], 0);
  LOADW10(WA, 0);

  for (int p = 0; p < 12; ++p) {          // handles mt = 2p, 2p+1
    const int mo1 = (2 * p + 1) * 64, mo2 = (2 * p + 2) * 64;
    STAGE10(lds[1], mo1);
    LOADW10(WB, mo1);
    SYNC_PRE;
    COMPUTE10(lds[0], WA);
    SYNC_POST;
    STAGE10(lds[0], mo2);                 // p=11: mt=24, offset 1536 < 1600
    LOADW10(WA, mo2);
    SYNC_PRE;
    COMPUTE10(lds[1], WB);
    SYNC_POST;
  }
  // epilogue: mt = 24 in lds[0]/WA
  asm volatile("s_waitcnt vmcnt(0)" ::: "memory");
  __builtin_amdgcn_sched_barrier(0);
  __builtin_amdgcn_s_barrier();
  __builtin_amdgcn_sched_barrier(0);
  COMPUTE10(lds[0], WA);
#undef STAGE10
#undef LOADW10
#undef SYNC_PRE
#undef SYNC_POST
#undef COMPUTE10

  // reduce the 16 k-slices (lanes differing in ks)
#pragma unroll
  for (int j = 0; j < 4; ++j)
#pragma unroll
    for (int u = 0; u < 12; ++u) {
      float v = acc[j][u];
      v += __shfl_xor(v, 8, 16);
      v += __shfl_xor(v, 4, 16);
      v += __shfl_xor(v, 2, 16);
      v += __shfl_xor(v, 1, 16);
      acc[j][u] = v;
    }
  if (ks == 0) {
#pragma unroll
    for (int j = 0; j < 4; ++j) {
      const int nglob = nbase + nq * 4 + j;
      if (nglob < N_NODES) {
#pragma unroll
        for (int u = 0; u < 12; ++u)
          part[((kc * 48 + t0 + u) << 10) + nglob] = acc[j][u];
      }
    }
  }
}

__global__ void k_reduce(const float* __restrict__ part, const float* __restrict__ blin,
                         float* __restrict__ outp) {
  const int id = blockIdx.x * 256 + threadIdx.x;
  if (id >= T_STEPS * N_NODES) return;
  const int t = id / N_NODES, n = id - t * N_NODES;
  float s = blin[n];
#pragma unroll
  for (int kc = 0; kc < KC4; ++kc) s += part[((kc * 48 + t) << 10) + n];
  outp[id] = s;
}

// ---------------- launch ----------------
extern "C" void kernel_launch(void* const* d_in, const int* in_sizes, int n_in,
                              void* d_out, int out_size, void* d_ws, size_t ws_size,
                              hipStream_t stream) {
  const float* x    = (const float*)d_in[0];
  const int*   ei   = (const int*)d_in[1];
  const float* h0   = (const float*)d_in[2];
  const float* c0   = (const float*)d_in[3];
  const float* Wg1  = (const float*)d_in[4];
  const float* bg1  = (const float*)d_in[5];
  const float* Wg2  = (const float*)d_in[6];
  const float* bg2  = (const float*)d_in[7];
  const float* Wih  = (const float*)d_in[8];
  const float* Whh  = (const float*)d_in[9];
  const float* bih  = (const float*)d_in[10];
  const float* bhh  = (const float*)d_in[11];
  const float* Wlin = (const float*)d_in[12];
  const float* blin = (const float*)d_in[13];
  float* outp = (float*)d_out;
  float* wsf  = (float*)d_ws;
  int*   wsi  = (int*)d_ws;

  int*   indeg  = wsi + O_INDEG;
  int*   fill   = wsi + O_FILL;
  int*   rowptr = wsi + O_ROWPTR;
  int*   csrc   = wsi + O_CSRC;
  float* cnorm  = wsf + O_CNORM;
  float* dinv   = wsf + O_DINV;
  float* selfn  = wsf + O_SELF;
  float* buf0   = wsf + O_BUF0;   // T1 -> T2 -> HS
  float* buf1   = wsf + O_BUF1;   // G1 -> G2 -> part

  k_zero<<<8, 256, 0, stream>>>(wsi);   // indeg[1000] + fill[1000]
  k_count<<<(E_EDGES + 255) / 256, 256, 0, stream>>>(ei, indeg);
  k_scan<<<1, 1024, 0, stream>>>(indeg, rowptr, dinv, selfn);
  k_scatter<<<(E_EDGES + 255) / 256, 256, 0, stream>>>(ei, rowptr, fill, dinv, csrc, cnorm);

  k_t1<<<750, 256, 0, stream>>>(x, Wg1, buf0);
  k_gath<<<3072, 256, 0, stream>>>(buf0, bg1, rowptr, csrc, cnorm, selfn, buf1, 1);  // G1
  k_mm2<<<750, 256, 0, stream>>>(buf1, Wg2, buf0);                                   // T2
  k_gath<<<3072, 256, 0, stream>>>(buf0, bg2, rowptr, csrc, cnorm, selfn, buf1, 0);  // G2
  k_lstm<<<1000, 256, 0, stream>>>(buf1, h0, c0, Wih, Whh, bih, bhh, buf0, outp);    // HS

  k_gemm10<<<KC4 * 63, 256, 0, stream>>>(buf0, Wlin, buf1);
  k_reduce<<<(T_STEPS * N_NODES + 255) / 256, 256, 0, stream>>>(buf1, blin, outp);
}

// Round 14
// 356.294 us; speedup vs baseline: 1.2340x; 1.2340x over previous
//
#include <hip/hip_runtime.h>
#include <math.h>

#define T_STEPS 48
#define N_NODES 1000
#define E_EDGES 32000
#define DIN     32
#define H_DIM   64

// ---- workspace layout (4-byte units) ----
#define O_INDEG  0         // int[1000]
#define O_FILL   1024      // int[1000]
#define O_ROWPTR 2048      // int[1001]
#define O_CSRC   4096      // int[32000]
#define O_CNORM  36864     // f32[32000]
#define O_DINV   69632     // f32[1000]
#define O_SELF   70656     // f32[1000]
#define O_BUF0   71680                    // f32[48*64000]  T1 -> T2 -> HS(f32) -> part
#define O_BUF1   (71680 + 3072000)        // f32[48*64000]  G1 -> G2 -> HS(bf16)

typedef __attribute__((ext_vector_type(8))) short short8;   // 8 bf16 (4 VGPR)
typedef __attribute__((ext_vector_type(4))) float f32x4;

__device__ __forceinline__ float sigmf(float v) { return 1.0f / (1.0f + __expf(-v)); }

// ---------------- setup ----------------
__global__ void k_zero(int* __restrict__ p) { p[blockIdx.x * 256 + threadIdx.x] = 0; }

__global__ void k_count(const int* __restrict__ ei, int* __restrict__ indeg) {
  int e = blockIdx.x * 256 + threadIdx.x;
  if (e < E_EDGES) atomicAdd(&indeg[ei[E_EDGES + e]], 1);
}

__global__ void k_scan(const int* __restrict__ indeg, int* __restrict__ rowptr,
                       float* __restrict__ dinv, float* __restrict__ selfn) {
  __shared__ int sdat[1024];
  int tid = threadIdx.x;
  int v = (tid < N_NODES) ? indeg[tid] : 0;
  sdat[tid] = v;
  __syncthreads();
  for (int off = 1; off < 1024; off <<= 1) {
    int add = (tid >= off) ? sdat[tid - off] : 0;
    __syncthreads();
    sdat[tid] += add;
    __syncthreads();
  }
  if (tid < N_NODES) {
    rowptr[tid + 1] = sdat[tid];
    float di = rsqrtf((float)(v + 1));
    dinv[tid] = di;
    selfn[tid] = di * di;
  }
  if (tid == 0) rowptr[0] = 0;
}

__global__ void k_scatter(const int* __restrict__ ei, const int* __restrict__ rowptr,
                          int* __restrict__ fill, const float* __restrict__ dinv,
                          int* __restrict__ csrc, float* __restrict__ cnorm) {
  int e = blockIdx.x * 256 + threadIdx.x;
  if (e >= E_EDGES) return;
  int s = ei[e], d = ei[E_EDGES + e];
  int pos = atomicAdd(&fill[d], 1);
  int idx = rowptr[d] + pos;
  csrc[idx] = s;
  cnorm[idx] = dinv[s] * dinv[d];
}

// ---------------- T1 = x @ Wg1 ----------------
__global__ void __launch_bounds__(256) k_t1(const float* __restrict__ x,
                                            const float* __restrict__ Wg1,
                                            float* __restrict__ T1) {
  __shared__ float sWT[H_DIM * 36];     // transposed: sWT[h][k]
  __shared__ float sx[4][DIN];
  const int tid = threadIdx.x, wv = tid >> 6, h = tid & 63;
  for (int i = tid; i < DIN * H_DIM; i += 256) sWT[(i & 63) * 36 + (i >> 6)] = Wg1[i];
  __syncthreads();
  const int r0 = blockIdx.x * 64 + wv * 16;
  const float4* wrow = (const float4*)&sWT[h * 36];
  for (int it = 0; it < 16; ++it) {
    const int r = r0 + it;
    if (h < DIN) sx[wv][h] = x[r * DIN + h];   // wave-local
    float acc = 0.f;
    const float4* xp = (const float4*)&sx[wv][0];
#pragma unroll
    for (int k4 = 0; k4 < 8; ++k4) {
      float4 xv = xp[k4], wv4 = wrow[k4];
      acc += xv.x * wv4.x + xv.y * wv4.y + xv.z * wv4.z + xv.w * wv4.w;
    }
    T1[r * H_DIM + h] = acc;
  }
}

// ---------------- gather: dst = gather(Tsrc)+self+bias, optional relu ----------------
__device__ __forceinline__ float gath_node(const float* __restrict__ Tsrc,
                                           const int* __restrict__ es,
                                           const float* __restrict__ ew,
                                           int cnt, int h) {
  float a0 = 0.f, a1 = 0.f, a2 = 0.f, a3 = 0.f;
  float a4 = 0.f, a5 = 0.f, a6 = 0.f, a7 = 0.f;
  int e = 0;
  if (cnt >= 8) {
    float p0 = Tsrc[es[0] * 64 + h], p1 = Tsrc[es[1] * 64 + h];
    float p2 = Tsrc[es[2] * 64 + h], p3 = Tsrc[es[3] * 64 + h];
    float p4 = Tsrc[es[4] * 64 + h], p5 = Tsrc[es[5] * 64 + h];
    float p6 = Tsrc[es[6] * 64 + h], p7 = Tsrc[es[7] * 64 + h];
    for (e = 8; e + 8 <= cnt; e += 8) {
      float n0 = Tsrc[es[e + 0] * 64 + h], n1 = Tsrc[es[e + 1] * 64 + h];
      float n2 = Tsrc[es[e + 2] * 64 + h], n3 = Tsrc[es[e + 3] * 64 + h];
      float n4 = Tsrc[es[e + 4] * 64 + h], n5 = Tsrc[es[e + 5] * 64 + h];
      float n6 = Tsrc[es[e + 6] * 64 + h], n7 = Tsrc[es[e + 7] * 64 + h];
      a0 += ew[e - 8] * p0; a1 += ew[e - 7] * p1;
      a2 += ew[e - 6] * p2; a3 += ew[e - 5] * p3;
      a4 += ew[e - 4] * p4; a5 += ew[e - 3] * p5;
      a6 += ew[e - 2] * p6; a7 += ew[e - 1] * p7;
      p0 = n0; p1 = n1; p2 = n2; p3 = n3; p4 = n4; p5 = n5; p6 = n6; p7 = n7;
    }
    a0 += ew[e - 8] * p0; a1 += ew[e - 7] * p1;
    a2 += ew[e - 6] * p2; a3 += ew[e - 5] * p3;
    a4 += ew[e - 4] * p4; a5 += ew[e - 3] * p5;
    a6 += ew[e - 2] * p6; a7 += ew[e - 1] * p7;
  }
  for (; e < cnt; ++e) a0 += ew[e] * Tsrc[es[e] * 64 + h];
  return ((a0 + a1) + (a2 + a3)) + ((a4 + a5) + (a6 + a7));
}

#define ECHUNK 768
__global__ void __launch_bounds__(256) k_gath(const float* __restrict__ Tall,
                                              const float* __restrict__ bias,
                                              const int* __restrict__ rowptr,
                                              const int* __restrict__ csrc,
                                              const float* __restrict__ cnorm,
                                              const float* __restrict__ selfn,
                                              float* __restrict__ Dall, int relu) {
  __shared__ int   s_src[ECHUNK];
  __shared__ float s_wt[ECHUNK];
  __shared__ float sb[64];
  const int tid = threadIdx.x, wv = tid >> 6, h = tid & 63;
  if (tid < 64) sb[tid] = bias[tid];
  const int t = blockIdx.x >> 6, nb16 = (blockIdx.x & 63) * 16;
  if (nb16 >= N_NODES) return;
  const float* Tsrc = Tall + t * 64000;
  float* dst = Dall + t * 64000;
  const int nE = (nb16 + 16 < N_NODES) ? nb16 + 16 : N_NODES;
  const int r0 = rowptr[nb16], r1 = rowptr[nE];
  const int tot = r1 - r0;
  const bool fits = (tot <= ECHUNK);
  if (fits)
    for (int i = tid; i < tot; i += 256) { s_src[i] = csrc[r0 + i]; s_wt[i] = cnorm[r0 + i]; }
  __syncthreads();
  for (int i = 0; i < 4; ++i) {
    const int n = nb16 + wv * 4 + i;
    if (n >= N_NODES) continue;
    const int a = rowptr[n], b = rowptr[n + 1];
    float acc = selfn[n] * Tsrc[n * 64 + h];
    if (fits) {
      acc += gath_node(Tsrc, s_src + (a - r0), s_wt + (a - r0), b - a, h);
    } else {
      for (int e = a; e < b; ++e) acc += cnorm[e] * Tsrc[csrc[e] * 64 + h];
    }
    acc += sb[h];
    if (relu) acc = fmaxf(acc, 0.f);
    dst[n * 64 + h] = acc;
  }
}

// ---------------- T2 = G1 @ Wg2 (48000 x 64 x 64) ----------------
__global__ void __launch_bounds__(256) k_mm2(const float* __restrict__ G1,
                                             const float* __restrict__ Wg2,
                                             float* __restrict__ T2) {
  __shared__ float sW[H_DIM * H_DIM];   // [k][h] broadcast form, conflict-free
  __shared__ float sx[4][H_DIM];
  const int tid = threadIdx.x, wv = tid >> 6, h = tid & 63;
  for (int i = tid; i < H_DIM * H_DIM; i += 256) sW[i] = Wg2[i];
  __syncthreads();
  const int r0 = blockIdx.x * 64 + wv * 16;
  for (int it = 0; it < 16; ++it) {
    const int r = r0 + it;
    sx[wv][h] = G1[r * 64 + h];   // wave-local write then read
    float acc = 0.f;
#pragma unroll
    for (int k = 0; k < H_DIM; ++k) acc += sx[wv][k] * sW[k * H_DIM + h];
    T2[r * 64 + h] = acc;
  }
}

// ---------------- LSTM scan: 1 node / block ----------------
__global__ void __launch_bounds__(256) k_lstm(const float* __restrict__ G2,
                                              const float* __restrict__ h0,
                                              const float* __restrict__ c0,
                                              const float* __restrict__ Wih,
                                              const float* __restrict__ Whh,
                                              const float* __restrict__ bih,
                                              const float* __restrict__ bhh,
                                              float* __restrict__ hsg,
                                              float* __restrict__ outp) {
  const int tid = threadIdx.x, nb = blockIdx.x;
  __shared__ float sh[64];
  __shared__ float sg2[2][64];
  __shared__ float sgates[256];
  float4 Wih4[16], Whh4[16];
  {
    const float4* wp = (const float4*)(Wih + tid * H_DIM);
    const float4* vp = (const float4*)(Whh + tid * H_DIM);
#pragma unroll
    for (int k = 0; k < 16; ++k) { Wih4[k] = wp[k]; Whh4[k] = vp[k]; }
  }
  const float bsum = bih[tid] + bhh[tid];
  float creg = 0.f;
  if (tid < 64) {
    sh[tid] = h0[nb * 64 + tid];
    creg = c0[nb * 64 + tid];
    sg2[0][tid] = G2[nb * 64 + tid];
  }
  __syncthreads();
  for (int t = 0; t < T_STEPS; ++t) {
    const int cur = t & 1;
    float gnext = 0.f;
    if (t < T_STEPS - 1 && tid < 64) gnext = G2[(t + 1) * 64000 + nb * 64 + tid];
    float gv = bsum;
    const float4* gp = (const float4*)&sg2[cur][0];
    const float4* hp = (const float4*)sh;
#pragma unroll
    for (int k = 0; k < 16; ++k) {
      float4 a = gp[k], b = hp[k];
      gv += a.x * Wih4[k].x + a.y * Wih4[k].y + a.z * Wih4[k].z + a.w * Wih4[k].w;
      gv += b.x * Whh4[k].x + b.y * Whh4[k].y + b.z * Whh4[k].z + b.w * Whh4[k].w;
    }
    sgates[tid] = gv;
    __syncthreads();
    if (tid < 64) {
      float iv = sgates[tid], fv = sgates[64 + tid], gg = sgates[128 + tid], ov = sgates[192 + tid];
      float cn = sigmf(fv) * creg + sigmf(iv) * tanhf(gg);
      float hn = sigmf(ov) * tanhf(cn);
      creg = cn;
      sh[tid] = hn;
      hsg[t * 64000 + nb * 64 + tid] = hn;
      if (t < T_STEPS - 1) sg2[cur ^ 1][tid] = gnext;
    }
    __syncthreads();
  }
  if (tid < 64) {
    outp[48000 + nb * 64 + tid] = sh[tid];
    outp[48000 + 64000 + nb * 64 + tid] = creg;
  }
}

// ---------------- HS f32 -> bf16 (once per launch) ----------------
__global__ void k_cvt(const float* __restrict__ src, unsigned* __restrict__ dst) {
  const int id = blockIdx.x * 256 + threadIdx.x;   // 768000 float4s
  const float4 v = ((const float4*)src)[id];
  unsigned lo, hi;
  asm("v_cvt_pk_bf16_f32 %0, %1, %2" : "=v"(lo) : "v"(v.x), "v"(v.y));
  asm("v_cvt_pk_bf16_f32 %0, %1, %2" : "=v"(hi) : "v"(v.z), "v"(v.w));
  ((uint2*)dst)[id] = make_uint2(lo, hi);
}

// ---------------- final projection: out = HS @ Wlin^T via bf16 MFMA ----------------
// Pure W-stream: no LDS, no barriers. Per K32-step/wave: 3 A-frag loads (bf16 HS,
// L2-hot), 2 W float4 loads, 4 cvt_pk (f32->bf16 in-register), 3 MFMA.
// grid 1008 = kc16 x nt63 (kc -> XCD, 16%8==0); wave w takes K-steps s≡w (mod 4).
// Partials: kp = kc*4+wv in [0,64); part[kp][48][1000] = buf0 exactly.
__global__ void __launch_bounds__(256) k_gemmM(const unsigned short* __restrict__ hsb,
                                               const float* __restrict__ Wlin,
                                               float* __restrict__ part) {
  const int tid = threadIdx.x;
  const int kc = blockIdx.x & 15, nt = blockIdx.x >> 4;   // kc->XCD; nt 0..62
  const int wv = tid >> 6, l = tid & 63;
  const int lr = l & 15, kg = l >> 4;       // in-tile row/col, k-group
  const int kcbase = kc * 4000;             // 64000/16
  const int kp = kc * 4 + wv;

  // A: HS_bf16[t = tt*16 + lr][kcbase + s*32 + kg*8 + i]
  const unsigned short* ap0 = hsb + (size_t)(0  + lr) * 64000 + kcbase + kg * 8 + wv * 32;
  const unsigned short* ap1 = hsb + (size_t)(16 + lr) * 64000 + kcbase + kg * 8 + wv * 32;
  const unsigned short* ap2 = hsb + (size_t)(32 + lr) * 64000 + kcbase + kg * 8 + wv * 32;
  // B: Wlin[n = nt*16 + lr][same k] f32 (row clamp for nt=62 tail handled at write)
  int nrow = nt * 16 + lr; if (nrow > N_NODES - 1) nrow = N_NODES - 1;
  const float* bp = Wlin + (size_t)nrow * 64000 + kcbase + kg * 8 + wv * 32;

  f32x4 acc0 = {0.f, 0.f, 0.f, 0.f}, acc1 = acc0, acc2 = acc0;

  for (int s = wv; s < 125; s += 4) {
    const short8 a0 = *(const short8*)ap0;
    const short8 a1 = *(const short8*)ap1;
    const short8 a2 = *(const short8*)ap2;
    const float4 b0 = *(const float4*)bp;
    const float4 b1 = *(const float4*)(bp + 4);
    unsigned p0, p1, p2, p3;
    asm("v_cvt_pk_bf16_f32 %0, %1, %2" : "=v"(p0) : "v"(b0.x), "v"(b0.y));
    asm("v_cvt_pk_bf16_f32 %0, %1, %2" : "=v"(p1) : "v"(b0.z), "v"(b0.w));
    asm("v_cvt_pk_bf16_f32 %0, %1, %2" : "=v"(p2) : "v"(b1.x), "v"(b1.y));
    asm("v_cvt_pk_bf16_f32 %0, %1, %2" : "=v"(p3) : "v"(b1.z), "v"(b1.w));
    union { unsigned u[4]; short8 s; } bu;
    bu.u[0] = p0; bu.u[1] = p1; bu.u[2] = p2; bu.u[3] = p3;
    acc0 = __builtin_amdgcn_mfma_f32_16x16x32_bf16(a0, bu.s, acc0, 0, 0, 0);
    acc1 = __builtin_amdgcn_mfma_f32_16x16x32_bf16(a1, bu.s, acc1, 0, 0, 0);
    acc2 = __builtin_amdgcn_mfma_f32_16x16x32_bf16(a2, bu.s, acc2, 0, 0, 0);
    ap0 += 128; ap1 += 128; ap2 += 128; bp += 128;   // 4 K-steps ahead
  }

  // C/D: col = l&15 (n), row = (l>>4)*4 + j (t within tile)
  const int n = nt * 16 + lr;
  if (n < N_NODES) {
    const int trow = kg * 4;
    float* base = part + (size_t)(kp * 48) * 1000 + n;
#pragma unroll
    for (int j = 0; j < 4; ++j) base[(0  + trow + j) * 1000] = acc0[j];
#pragma unroll
    for (int j = 0; j < 4; ++j) base[(16 + trow + j) * 1000] = acc1[j];
#pragma unroll
    for (int j = 0; j < 4; ++j) base[(32 + trow + j) * 1000] = acc2[j];
  }
}

__global__ void k_reduce(const float* __restrict__ part, const float* __restrict__ blin,
                         float* __restrict__ outp) {
  const int id = blockIdx.x * 256 + threadIdx.x;
  if (id >= T_STEPS * N_NODES) return;
  const int t = id / N_NODES, n = id - t * N_NODES;
  float s = blin[n];
#pragma unroll 8
  for (int kp = 0; kp < 64; ++kp) s += part[(size_t)(kp * 48 + t) * 1000 + n];
  outp[id] = s;
}

// ---------------- launch ----------------
extern "C" void kernel_launch(void* const* d_in, const int* in_sizes, int n_in,
                              void* d_out, int out_size, void* d_ws, size_t ws_size,
                              hipStream_t stream) {
  const float* x    = (const float*)d_in[0];
  const int*   ei   = (const int*)d_in[1];
  const float* h0   = (const float*)d_in[2];
  const float* c0   = (const float*)d_in[3];
  const float* Wg1  = (const float*)d_in[4];
  const float* bg1  = (const float*)d_in[5];
  const float* Wg2  = (const float*)d_in[6];
  const float* bg2  = (const float*)d_in[7];
  const float* Wih  = (const float*)d_in[8];
  const float* Whh  = (const float*)d_in[9];
  const float* bih  = (const float*)d_in[10];
  const float* bhh  = (const float*)d_in[11];
  const float* Wlin = (const float*)d_in[12];
  const float* blin = (const float*)d_in[13];
  float* outp = (float*)d_out;
  float* wsf  = (float*)d_ws;
  int*   wsi  = (int*)d_ws;

  int*   indeg  = wsi + O_INDEG;
  int*   fill   = wsi + O_FILL;
  int*   rowptr = wsi + O_ROWPTR;
  int*   csrc   = wsi + O_CSRC;
  float* cnorm  = wsf + O_CNORM;
  float* dinv   = wsf + O_DINV;
  float* selfn  = wsf + O_SELF;
  float* buf0   = wsf + O_BUF0;   // T1 -> T2 -> HS(f32) -> part
  float* buf1   = wsf + O_BUF1;   // G1 -> G2 -> HS(bf16)

  k_zero<<<8, 256, 0, stream>>>(wsi);   // indeg[1000] + fill[1000]
  k_count<<<(E_EDGES + 255) / 256, 256, 0, stream>>>(ei, indeg);
  k_scan<<<1, 1024, 0, stream>>>(indeg, rowptr, dinv, selfn);
  k_scatter<<<(E_EDGES + 255) / 256, 256, 0, stream>>>(ei, rowptr, fill, dinv, csrc, cnorm);

  k_t1<<<750, 256, 0, stream>>>(x, Wg1, buf0);
  k_gath<<<3072, 256, 0, stream>>>(buf0, bg1, rowptr, csrc, cnorm, selfn, buf1, 1);  // G1
  k_mm2<<<750, 256, 0, stream>>>(buf1, Wg2, buf0);                                   // T2
  k_gath<<<3072, 256, 0, stream>>>(buf0, bg2, rowptr, csrc, cnorm, selfn, buf1, 0);  // G2
  k_lstm<<<1000, 256, 0, stream>>>(buf1, h0, c0, Wih, Whh, bih, bhh, buf0, outp);    // HS f32

  // HS f32 (buf0) -> bf16 (buf1); then buf0 becomes the partials buffer
  k_cvt<<<3000, 256, 0, stream>>>(buf0, (unsigned*)buf1);
  k_gemmM<<<16 * 63, 256, 0, stream>>>((const unsigned short*)buf1, Wlin, buf0);
  k_reduce<<<(T_STEPS * N_NODES + 255) / 256, 256, 0, stream>>>(buf0, blin, outp);
}